// Round 1
// baseline (235.977 us; speedup 1.0000x reference)
//
#include <hip/hip_runtime.h>
#include <hip/hip_bf16.h>

// Sizes (fixed by the problem)
#define HDIM 512
#define BB 32
#define SS 4096
#define BS 64            // s-rows per k_main block
#define NCHUNK (SS/BS)   // 64 chunks per b

typedef __attribute__((ext_vector_type(8))) short short8;   // 8 x bf16 (4 VGPRs)
typedef __attribute__((ext_vector_type(4))) float f32x4;

// Workspace layout (bytes)
#define WS_QB   0                         // 32*512*4   = 65536
#define WS_WRB  65536                     // 512*512*2  = 524288
#define WS_PM   (65536+524288)            // 2048*4
#define WS_PD   (WS_PM+8192)              // 2048*4
#define WS_PU   (WS_PD+8192)              // 2048*512*4 = 4 MB  (total ~4.8 MB)

__device__ __forceinline__ unsigned short f2bf(float f){
  unsigned u = __float_as_uint(f);
  u += 0x7FFFu + ((u >> 16) & 1u);        // RNE
  return (unsigned short)(u >> 16);
}

__device__ __forceinline__ float fast_tanh(float x){
  float e = __expf(2.f * x);
  return 1.f - __fdividef(2.f, 1.f + e);
}

// ---------------- K1: qb[b,h] = bq[h] + br[h] + sum_k query[b,k]*Wq[h,k] ----------------
__global__ __launch_bounds__(256) void k_qproj(const float* __restrict__ query,
                                               const float* __restrict__ Wq,
                                               const float* __restrict__ bq,
                                               const float* __restrict__ br,
                                               float* __restrict__ qb){
  int b = blockIdx.x, t = threadIdx.x;
  __shared__ __align__(16) float sq[HDIM];
  sq[t] = query[b*HDIM + t];
  sq[t+256] = query[b*HDIM + t + 256];
  __syncthreads();
  const f32x4* sq4 = (const f32x4*)sq;
  for (int hh = 0; hh < 2; ++hh){
    int h = t + hh*256;
    const f32x4* w4 = (const f32x4*)(Wq + (size_t)h*HDIM);
    float acc = bq[h] + br[h];
    #pragma unroll 4
    for (int k = 0; k < HDIM/4; ++k){
      f32x4 w = w4[k]; f32x4 q = sq4[k];
      acc += w.x*q.x + w.y*q.y + w.z*q.z + w.w*q.w;
    }
    qb[b*HDIM + h] = acc;
  }
}

// ---------------- K1b: Wr f32 -> bf16 ----------------
__global__ __launch_bounds__(256) void k_cvt_wr(const float* __restrict__ Wr,
                                                unsigned short* __restrict__ wrb){
  int idx = blockIdx.x*256 + threadIdx.x;      // 65536 threads, 4 elems each
  f32x4 v = ((const f32x4*)Wr)[idx];
  ushort4 o;
  o.x = f2bf(v.x); o.y = f2bf(v.y); o.z = f2bf(v.z); o.w = f2bf(v.w);
  ((ushort4*)wrb)[idx] = o;
}

// ---------------- K2: main fused kernel ----------------
// Per block: b = bid>>6, chunk = bid&63 (64 s-rows).
//  1) stage ref[b, s0:s0+64, :] f32->bf16 into swizzled LDS (64KB)
//  2) GEMM r = A @ Wr^T via mfma 16x16x32 bf16; B-frags read straight from global (L2)
//  3) epilogue: logits[s] = sum_h V[h]*tanh(qb[h]+r[s,h])  (cross-lane reduce)
//  4) chunk softmax partials m,d ; u[k] = sum_s e_s * A[s,k] from LDS
__global__ __launch_bounds__(256, 2) void k_main(const float* __restrict__ ref,
                                                 const unsigned short* __restrict__ wrb,
                                                 const float* __restrict__ qb,
                                                 const float* __restrict__ V,
                                                 float* __restrict__ pm,
                                                 float* __restrict__ pd,
                                                 float* __restrict__ pu){
  int bid = blockIdx.x;
  int b = bid >> 6;
  int chunk = bid & 63;
  int s0 = chunk * BS;
  int tid = threadIdx.x;
  int w = tid >> 6, lane = tid & 63;
  int lo16 = lane & 15, g = lane >> 4;

  __shared__ __align__(16) unsigned short sA[BS*HDIM]; // 64KB, rows XOR-swizzled
  __shared__ __align__(16) float sQb[HDIM];
  __shared__ __align__(16) float sV[HDIM];
  __shared__ float sLog[4][BS];
  __shared__ float sE[BS];

  for (int i = tid; i < HDIM; i += 256){
    sQb[i] = qb[b*HDIM + i];
    sV[i]  = V[i];
  }

  // ---- stage A (64 x 512 f32 -> bf16, swizzle byte ^= (row&7)<<4) ----
  {
    const f32x4* src4 = (const f32x4*)(ref + ((size_t)b*SS + s0)*HDIM);
    #pragma unroll 4
    for (int i = 0; i < 32; ++i){
      int idx = tid + 256*i;                 // 8192 float4 chunks
      int row = idx >> 7, c = idx & 127;
      f32x4 v = src4[idx];
      ushort4 o;
      o.x = f2bf(v.x); o.y = f2bf(v.y); o.z = f2bf(v.z); o.w = f2bf(v.w);
      unsigned byte = ((unsigned)(row*1024 + c*8)) ^ ((unsigned)(row & 7) << 4);
      *(ushort4*)((char*)sA + byte) = o;
    }
  }
  __syncthreads();

  // ---- GEMM: each wave covers cols [w*128, w*128+128), all 64 rows ----
  f32x4 acc[4][8];
  #pragma unroll
  for (int m = 0; m < 4; ++m)
    #pragma unroll
    for (int n = 0; n < 8; ++n)
      acc[m][n] = (f32x4){0.f, 0.f, 0.f, 0.f};

  int colbase = w*128 + lo16;

  #pragma unroll 2
  for (int kt = 0; kt < 16; ++kt){
    short8 af[4];
    #pragma unroll
    for (int m = 0; m < 4; ++m){
      int row = 16*m + lo16;
      unsigned byte = ((unsigned)(row*1024 + kt*64 + g*16)) ^ ((unsigned)(row & 7) << 4);
      af[m] = *(const short8*)((const char*)sA + byte);
    }
    short8 bfr[8];
    #pragma unroll
    for (int n = 0; n < 8; ++n){
      int col = colbase + n*16;
      bfr[n] = *(const short8*)(wrb + (size_t)col*HDIM + kt*32 + g*8);
    }
    #pragma unroll
    for (int m = 0; m < 4; ++m)
      #pragma unroll
      for (int n = 0; n < 8; ++n)
        acc[m][n] = __builtin_amdgcn_mfma_f32_16x16x32_bf16(af[m], bfr[n], acc[m][n], 0, 0, 0);
  }

  // ---- epilogue: logits partials. D-layout: col=lane&15, row=16m+4g+r ----
  float lacc[4][4];
  #pragma unroll
  for (int m = 0; m < 4; ++m)
    #pragma unroll
    for (int r = 0; r < 4; ++r)
      lacc[m][r] = 0.f;

  #pragma unroll
  for (int n = 0; n < 8; ++n){
    int col = colbase + n*16;
    float qv = sQb[col], vv = sV[col];
    #pragma unroll
    for (int m = 0; m < 4; ++m)
      #pragma unroll
      for (int r = 0; r < 4; ++r){
        float x = qv + acc[m][n][r];
        lacc[m][r] += vv * fast_tanh(x);
      }
  }
  #pragma unroll
  for (int m = 0; m < 4; ++m)
    #pragma unroll
    for (int r = 0; r < 4; ++r){
      float v = lacc[m][r];
      v += __shfl_xor(v, 1); v += __shfl_xor(v, 2);
      v += __shfl_xor(v, 4); v += __shfl_xor(v, 8);
      lacc[m][r] = v;
    }
  if (lo16 == 0){
    #pragma unroll
    for (int m = 0; m < 4; ++m)
      #pragma unroll
      for (int r = 0; r < 4; ++r)
        sLog[w][16*m + 4*g + r] = lacc[m][r];
  }
  __syncthreads();

  // ---- chunk softmax partials (wave 0) ----
  if (w == 0){
    float l = sLog[0][lane] + sLog[1][lane] + sLog[2][lane] + sLog[3][lane];
    float mx = l;
    mx = fmaxf(mx, __shfl_xor(mx, 1));  mx = fmaxf(mx, __shfl_xor(mx, 2));
    mx = fmaxf(mx, __shfl_xor(mx, 4));  mx = fmaxf(mx, __shfl_xor(mx, 8));
    mx = fmaxf(mx, __shfl_xor(mx, 16)); mx = fmaxf(mx, __shfl_xor(mx, 32));
    float e = __expf(l - mx);
    float d = e;
    d += __shfl_xor(d, 1); d += __shfl_xor(d, 2); d += __shfl_xor(d, 4);
    d += __shfl_xor(d, 8); d += __shfl_xor(d, 16); d += __shfl_xor(d, 32);
    sE[lane] = e;
    if (lane == 0){ pm[bid] = mx; pd[bid] = d; }
  }
  __syncthreads();

  // ---- u[k] = sum_s e_s * A[s,k]  (k = 2*tid, 2*tid+1) ----
  float u0 = 0.f, u1 = 0.f;
  #pragma unroll 4
  for (int s = 0; s < BS; ++s){
    unsigned byte = ((unsigned)(s*1024 + tid*4)) ^ ((unsigned)(s & 7) << 4);
    unsigned pk = *(const unsigned*)((const char*)sA + byte);
    float e = sE[s];
    u0 += e * __uint_as_float((pk & 0xFFFFu) << 16);
    u1 += e * __uint_as_float(pk & 0xFFFF0000u);
  }
  pu[(size_t)bid*HDIM + 2*tid]     = u0;
  pu[(size_t)bid*HDIM + 2*tid + 1] = u1;
}

// ---------------- K3: combine partials + out = Wr @ u + br ----------------
__global__ __launch_bounds__(256) void k_final(const float* __restrict__ Wr,
                                               const float* __restrict__ br,
                                               const float* __restrict__ pm,
                                               const float* __restrict__ pd,
                                               const float* __restrict__ pu,
                                               float* __restrict__ out){
  int b = blockIdx.x, t = threadIdx.x, lane = t & 63, w = t >> 6;
  __shared__ float sSc[NCHUNK];
  __shared__ __align__(16) float sU[HDIM];
  __shared__ float sMD[1];

  if (w == 0){
    float m = pm[b*64 + lane];
    float mx = m;
    mx = fmaxf(mx, __shfl_xor(mx, 1));  mx = fmaxf(mx, __shfl_xor(mx, 2));
    mx = fmaxf(mx, __shfl_xor(mx, 4));  mx = fmaxf(mx, __shfl_xor(mx, 8));
    mx = fmaxf(mx, __shfl_xor(mx, 16)); mx = fmaxf(mx, __shfl_xor(mx, 32));
    float sc = __expf(m - mx);
    float d = sc * pd[b*64 + lane];
    d += __shfl_xor(d, 1); d += __shfl_xor(d, 2); d += __shfl_xor(d, 4);
    d += __shfl_xor(d, 8); d += __shfl_xor(d, 16); d += __shfl_xor(d, 32);
    sSc[lane] = sc;
    if (lane == 0) sMD[0] = d;
  }
  __syncthreads();

  float inv = 1.f / sMD[0];
  float u0 = 0.f, u1 = 0.f;
  for (int c = 0; c < NCHUNK; ++c){
    float sc = sSc[c];
    const float* p = pu + ((size_t)(b*64 + c))*HDIM;
    u0 += sc * p[t];
    u1 += sc * p[t+256];
  }
  sU[t]     = u0 * inv;
  sU[t+256] = u1 * inv;
  __syncthreads();

  const f32x4* su4 = (const f32x4*)sU;
  for (int hh = 0; hh < 2; ++hh){
    int h = t + hh*256;
    const f32x4* w4 = (const f32x4*)(Wr + (size_t)h*HDIM);
    float acc = br[h];
    #pragma unroll 4
    for (int k = 0; k < HDIM/4; ++k){
      f32x4 wv = w4[k], uv = su4[k];
      acc += wv.x*uv.x + wv.y*uv.y + wv.z*uv.z + wv.w*uv.w;
    }
    out[b*HDIM + h] = acc;
  }
}

extern "C" void kernel_launch(void* const* d_in, const int* in_sizes, int n_in,
                              void* d_out, int out_size, void* d_ws, size_t ws_size,
                              hipStream_t stream){
  const float* query = (const float*)d_in[0];
  const float* ref   = (const float*)d_in[1];
  const float* Wq    = (const float*)d_in[2];
  const float* bq    = (const float*)d_in[3];
  const float* Wr    = (const float*)d_in[4];
  const float* br    = (const float*)d_in[5];
  const float* V     = (const float*)d_in[6];
  char* ws = (char*)d_ws;
  float*          qbv = (float*)(ws + WS_QB);
  unsigned short* wrb = (unsigned short*)(ws + WS_WRB);
  float*          pm  = (float*)(ws + WS_PM);
  float*          pd  = (float*)(ws + WS_PD);
  float*          pu  = (float*)(ws + WS_PU);
  float* out = (float*)d_out;

  k_qproj<<<dim3(BB), dim3(256), 0, stream>>>(query, Wq, bq, br, qbv);
  k_cvt_wr<<<dim3(256), dim3(256), 0, stream>>>(Wr, wrb);
  k_main<<<dim3(BB*NCHUNK), dim3(256), 0, stream>>>(ref, wrb, qbv, V, pm, pd, pu);
  k_final<<<dim3(BB), dim3(256), 0, stream>>>(Wr, br, pm, pd, pu, out);
}